// Round 2
// baseline (1537.964 us; speedup 1.0000x reference)
//
#include <hip/hip_runtime.h>

#define F 128            // F_IN == F_OUT == 128
#define BM 64
#define BK 64
#define EPSV 1e-5f

// K1: scatter-add aggregation. 32 threads per edge, 4 features per thread.
__global__ __launch_bounds__(256) void k_scatter(
        const float* __restrict__ x,
        const int* __restrict__ src, const int* __restrict__ dst,
        const float* __restrict__ we,
        float* __restrict__ agg, int E) {
    int gid = blockIdx.x * 256 + threadIdx.x;
    int e = gid >> 5;
    if (e >= E) return;
    int part = gid & 31;
    int s = src[e], d = dst[e];
    float w = we[e];
    int f = part * 4;
    float4 v = *reinterpret_cast<const float4*>(x + (size_t)s * F + f);
    float* ap = agg + (size_t)d * F + f;
    atomicAdd(ap + 0, w * v.x);
    atomicAdd(ap + 1, w * v.y);
    atomicAdd(ap + 2, w * v.z);
    atomicAdd(ap + 3, w * v.w);
}

// K2: y[n,o] = sum_k x[n,k]*W[o,k] + sum_k agg[n,k]*W[o,128+k]  (f32 vector GEMM)
// Block: 256 threads, tile 64 rows x 128 cols, BK=64 chunks (2 from x, 2 from agg).
// Thread (co = t&31, ro = t>>5) owns cols co*4..co*4+3, rows ro*8..ro*8+7.
__global__ __launch_bounds__(256) void k_gemm(
        const float* __restrict__ x, const float* __restrict__ agg,
        const float* __restrict__ W, float* __restrict__ y, int N) {
    __shared__ float wlds[BK][132];  // [k][o], stride 132 floats (16B-aligned rows for co*4 float4 reads)
    __shared__ float hlds[BM][68];   // [row][k], stride 68 floats (16B-aligned, bank-balanced)
    int t = threadIdx.x;
    int co = t & 31, ro = t >> 5;
    int row0 = blockIdx.x * BM;
    float acc[8][4] = {};
    for (int kc = 0; kc < 4; ++kc) {
        int kbase = kc * 64;
        // stage W chunk: global [o][k] -> LDS [k][o] (transpose; coalesced global reads)
        #pragma unroll
        for (int i = 0; i < 32; ++i) {
            int idx = t + i * 256;
            int k = idx & 63, o = idx >> 6;
            wlds[k][o] = W[o * 256 + kbase + k];
        }
        // stage h chunk: rows row0..row0+63, k from x (kc<2) or agg (kc>=2)
        #pragma unroll
        for (int i = 0; i < 4; ++i) {
            int r = i * 16 + (t >> 4);
            int k4 = (t & 15) * 4;
            int gr = row0 + r;
            float4 v = make_float4(0.f, 0.f, 0.f, 0.f);
            if (gr < N) {
                if (kc < 2) {
                    v = *reinterpret_cast<const float4*>(
                        x + (size_t)gr * F + kc * 64 + k4);
                } else {
                    v = *reinterpret_cast<const float4*>(
                        agg + (size_t)gr * F + (kc - 2) * 64 + k4);
                }
            }
            *reinterpret_cast<float4*>(&hlds[r][k4]) = v;
        }
        __syncthreads();
        #pragma unroll
        for (int k = 0; k < BK; k += 4) {
            float4 h4[8];
            #pragma unroll
            for (int j = 0; j < 8; ++j)
                h4[j] = *reinterpret_cast<const float4*>(&hlds[ro * 8 + j][k]);
            #pragma unroll
            for (int kk = 0; kk < 4; ++kk) {
                float4 w4 = *reinterpret_cast<const float4*>(&wlds[k + kk][co * 4]);
                #pragma unroll
                for (int j = 0; j < 8; ++j) {
                    float hv = reinterpret_cast<const float*>(&h4[j])[kk];
                    acc[j][0] = fmaf(hv, w4.x, acc[j][0]);
                    acc[j][1] = fmaf(hv, w4.y, acc[j][1]);
                    acc[j][2] = fmaf(hv, w4.z, acc[j][2]);
                    acc[j][3] = fmaf(hv, w4.w, acc[j][3]);
                }
            }
        }
        __syncthreads();
    }
    #pragma unroll
    for (int j = 0; j < 8; ++j) {
        int gr = row0 + ro * 8 + j;
        if (gr < N) {
            *reinterpret_cast<float4*>(y + (size_t)gr * F + co * 4) =
                make_float4(acc[j][0], acc[j][1], acc[j][2], acc[j][3]);
        }
    }
}

// K3: per-column sum and sum-of-squares over rows
__global__ __launch_bounds__(256) void k_stats(
        const float* __restrict__ y, float* __restrict__ colsum,
        float* __restrict__ colsumsq, int N) {
    __shared__ float ls[256], lss[256];
    int t = threadIdx.x;
    int col = t & 127, half = t >> 7;
    float s = 0.f, ss = 0.f;
    for (int r = blockIdx.x * 2 + half; r < N; r += gridDim.x * 2) {
        float v = y[(size_t)r * F + col];
        s += v; ss += v * v;
    }
    ls[t] = s; lss[t] = ss;
    __syncthreads();
    if (t < 128) {
        atomicAdd(&colsum[col], ls[t] + ls[t + 128]);
        atomicAdd(&colsumsq[col], lss[t] + lss[t + 128]);
    }
}

// K4: per-column scale/shift
__global__ void k_finalize(const float* __restrict__ colsum,
                           const float* __restrict__ colsumsq,
                           const float* __restrict__ gamma,
                           const float* __restrict__ beta,
                           float* __restrict__ scaleshift, float ninv) {
    int o = threadIdx.x;
    float mean = colsum[o] * ninv;
    float var = colsumsq[o] * ninv - mean * mean;
    float rstd = rsqrtf(var + EPSV);
    float sc = gamma[o] * rstd;
    scaleshift[o] = sc;
    scaleshift[F + o] = beta[o] - mean * sc;
}

// K5: normalize in place (elementwise on y == d_out)
__global__ __launch_bounds__(256) void k_norm(
        float* __restrict__ y, const float* __restrict__ scaleshift,
        int total4) {
    int idx = blockIdx.x * 256 + threadIdx.x;
    if (idx >= total4) return;
    int col4 = (idx & 31) * 4;
    float4 v = *reinterpret_cast<const float4*>(y + (size_t)idx * 4);
    float4 o4;
    o4.x = v.x * scaleshift[col4 + 0] + scaleshift[F + col4 + 0];
    o4.y = v.y * scaleshift[col4 + 1] + scaleshift[F + col4 + 1];
    o4.z = v.z * scaleshift[col4 + 2] + scaleshift[F + col4 + 2];
    o4.w = v.w * scaleshift[col4 + 3] + scaleshift[F + col4 + 3];
    *reinterpret_cast<float4*>(y + (size_t)idx * 4) = o4;
}

extern "C" void kernel_launch(void* const* d_in, const int* in_sizes, int n_in,
                              void* d_out, int out_size, void* d_ws, size_t ws_size,
                              hipStream_t stream) {
    (void)n_in; (void)out_size; (void)ws_size;
    const float* x     = (const float*)d_in[0];
    const int*   src   = (const int*)d_in[1];
    const int*   dst   = (const int*)d_in[2];
    const float* we    = (const float*)d_in[3];
    const float* W     = (const float*)d_in[4];
    const float* gamma = (const float*)d_in[5];
    const float* beta  = (const float*)d_in[6];
    int N = in_sizes[0] / F;
    int E = in_sizes[1];

    float* agg        = (float*)d_ws;                 // N*F
    float* colsum     = agg + (size_t)N * F;          // F
    float* colsumsq   = colsum + F;                   // F
    float* scaleshift = colsumsq + F;                 // 2*F
    float* y          = (float*)d_out;                // N*F, normalized in place

    hipMemsetAsync(agg, 0, (size_t)N * F * sizeof(float), stream);
    hipMemsetAsync(colsum, 0, 2 * F * sizeof(float), stream);

    int nb1 = (E * 32 + 255) / 256;
    hipLaunchKernelGGL(k_scatter, dim3(nb1), dim3(256), 0, stream,
                       x, src, dst, we, agg, E);
    hipLaunchKernelGGL(k_gemm, dim3((N + BM - 1) / BM), dim3(256), 0, stream,
                       x, agg, W, y, N);
    hipLaunchKernelGGL(k_stats, dim3(256), dim3(256), 0, stream,
                       y, colsum, colsumsq, N);
    hipLaunchKernelGGL(k_finalize, dim3(1), dim3(F), 0, stream,
                       colsum, colsumsq, gamma, beta, scaleshift, 1.0f / (float)N);
    hipLaunchKernelGGL(k_norm, dim3((N * 32 + 255) / 256), dim3(256), 0, stream,
                       y, scaleshift, N * 32);
}

// Round 3
// 351.002 us; speedup vs baseline: 4.3816x; 4.3816x over previous
//
#include <hip/hip_runtime.h>

#define F 128            // F_IN == F_OUT == 128
#define BM 64
#define BK 64
#define EPSV 1e-5f

// ---------------- CSR build ----------------

// H1: histogram of dst
__global__ __launch_bounds__(256) void k_hist(
        const int* __restrict__ dst, int* __restrict__ counts, int E) {
    int e = blockIdx.x * 256 + threadIdx.x;
    if (e < E) atomicAdd(&counts[dst[e]], 1);
}

// S1: per-chunk (1024 elems) exclusive scan; chunk totals -> partials
__global__ __launch_bounds__(256) void k_scan1(
        const int* __restrict__ counts, int* __restrict__ rowptr,
        int* __restrict__ partials, int N) {
    __shared__ int wsum[4];
    int t = threadIdx.x;
    int base = blockIdx.x * 1024;
    int lane = t & 63, wv = t >> 6;
    int v[4], s = 0;
    #pragma unroll
    for (int i = 0; i < 4; ++i) {
        int idx = base + t * 4 + i;
        v[i] = (idx < N) ? counts[idx] : 0;
        s += v[i];
    }
    int sc = s;
    #pragma unroll
    for (int off = 1; off < 64; off <<= 1) {
        int o = __shfl_up(sc, off);
        if (lane >= off) sc += o;
    }
    if (lane == 63) wsum[wv] = sc;
    __syncthreads();
    int woff = 0;
    for (int i = 0; i < wv; ++i) woff += wsum[i];
    int excl = woff + sc - s;
    #pragma unroll
    for (int i = 0; i < 4; ++i) {
        int idx = base + t * 4 + i;
        if (idx < N) rowptr[idx] = excl;
        excl += v[i];
    }
    if (t == 255) partials[blockIdx.x] = woff + sc;
}

// S2: exclusive scan of chunk totals (single wave, generic nb)
__global__ void k_scan2(int* __restrict__ partials, int nb) {
    int t = threadIdx.x;  // 64 threads
    int carry = 0;
    for (int b = 0; b < nb; b += 64) {
        int i = b + t;
        int v = (i < nb) ? partials[i] : 0;
        int sc = v;
        #pragma unroll
        for (int off = 1; off < 64; off <<= 1) {
            int o = __shfl_up(sc, off);
            if (t >= off) sc += o;
        }
        if (i < nb) partials[i] = carry + sc - v;
        carry += __shfl(sc, 63);
    }
}

// S3: add chunk offsets; init cursor = rowptr
__global__ __launch_bounds__(256) void k_scan3(
        int* __restrict__ rowptr, int* __restrict__ cursor,
        const int* __restrict__ partials, int N) {
    int idx = blockIdx.x * 256 + threadIdx.x;
    if (idx >= N) return;
    int r = rowptr[idx] + partials[idx >> 10];
    rowptr[idx] = r;
    cursor[idx] = r;
}

// F1: scatter edge payloads into CSR slots
__global__ __launch_bounds__(256) void k_fill(
        const int* __restrict__ src, const int* __restrict__ dst,
        const float* __restrict__ we, int* __restrict__ cursor,
        int* __restrict__ esrc, float* __restrict__ ew, int E) {
    int e = blockIdx.x * 256 + threadIdx.x;
    if (e >= E) return;
    int d = dst[e];
    int slot = atomicAdd(&cursor[d], 1);
    esrc[slot] = src[e];
    ew[slot]   = we[e];
}

// A1: pull-mode aggregation. One wave per node; 64 lanes x float2 = 128 feats.
__global__ __launch_bounds__(256) void k_agg(
        const float* __restrict__ x, const int* __restrict__ rowptr,
        const int* __restrict__ counts, const int* __restrict__ esrc,
        const float* __restrict__ ew, float* __restrict__ agg, int N) {
    int wv = threadIdx.x >> 6, lane = threadIdx.x & 63;
    int n = blockIdx.x * 4 + wv;
    if (n >= N) return;
    int beg = rowptr[n], cnt = counts[n];
    float2 acc = make_float2(0.f, 0.f);
    int i = 0;
    for (; i + 2 <= cnt; i += 2) {
        int   s0 = esrc[beg + i],     s1 = esrc[beg + i + 1];
        float w0 = ew[beg + i],       w1 = ew[beg + i + 1];
        float2 v0 = *reinterpret_cast<const float2*>(x + (size_t)s0 * F + lane * 2);
        float2 v1 = *reinterpret_cast<const float2*>(x + (size_t)s1 * F + lane * 2);
        acc.x += w0 * v0.x + w1 * v1.x;
        acc.y += w0 * v0.y + w1 * v1.y;
    }
    if (i < cnt) {
        int   s0 = esrc[beg + i];
        float w0 = ew[beg + i];
        float2 v0 = *reinterpret_cast<const float2*>(x + (size_t)s0 * F + lane * 2);
        acc.x += w0 * v0.x;
        acc.y += w0 * v0.y;
    }
    *reinterpret_cast<float2*>(agg + (size_t)n * F + lane * 2) = acc;
}

// ---------------- fallback: atomic scatter (if ws too small) ----------------
__global__ __launch_bounds__(256) void k_scatter(
        const float* __restrict__ x,
        const int* __restrict__ src, const int* __restrict__ dst,
        const float* __restrict__ we,
        float* __restrict__ agg, int E) {
    int gid = blockIdx.x * 256 + threadIdx.x;
    int e = gid >> 5;
    if (e >= E) return;
    int part = gid & 31;
    int s = src[e], d = dst[e];
    float w = we[e];
    int f = part * 4;
    float4 v = *reinterpret_cast<const float4*>(x + (size_t)s * F + f);
    float* ap = agg + (size_t)d * F + f;
    atomicAdd(ap + 0, w * v.x);
    atomicAdd(ap + 1, w * v.y);
    atomicAdd(ap + 2, w * v.z);
    atomicAdd(ap + 3, w * v.w);
}

// ---------------- GEMM: y = [x, agg] @ W^T ----------------
__global__ __launch_bounds__(256) void k_gemm(
        const float* __restrict__ x, const float* __restrict__ agg,
        const float* __restrict__ W, float* __restrict__ y, int N) {
    __shared__ float wlds[BK][132];
    __shared__ float hlds[BM][68];
    int t = threadIdx.x;
    int co = t & 31, ro = t >> 5;
    int row0 = blockIdx.x * BM;
    float acc[8][4] = {};
    for (int kc = 0; kc < 4; ++kc) {
        int kbase = kc * 64;
        #pragma unroll
        for (int i = 0; i < 32; ++i) {
            int idx = t + i * 256;
            int k = idx & 63, o = idx >> 6;
            wlds[k][o] = W[o * 256 + kbase + k];
        }
        #pragma unroll
        for (int i = 0; i < 4; ++i) {
            int r = i * 16 + (t >> 4);
            int k4 = (t & 15) * 4;
            int gr = row0 + r;
            float4 v = make_float4(0.f, 0.f, 0.f, 0.f);
            if (gr < N) {
                if (kc < 2) {
                    v = *reinterpret_cast<const float4*>(
                        x + (size_t)gr * F + kc * 64 + k4);
                } else {
                    v = *reinterpret_cast<const float4*>(
                        agg + (size_t)gr * F + (kc - 2) * 64 + k4);
                }
            }
            *reinterpret_cast<float4*>(&hlds[r][k4]) = v;
        }
        __syncthreads();
        #pragma unroll
        for (int k = 0; k < BK; k += 4) {
            float4 h4[8];
            #pragma unroll
            for (int j = 0; j < 8; ++j)
                h4[j] = *reinterpret_cast<const float4*>(&hlds[ro * 8 + j][k]);
            #pragma unroll
            for (int kk = 0; kk < 4; ++kk) {
                float4 w4 = *reinterpret_cast<const float4*>(&wlds[k + kk][co * 4]);
                #pragma unroll
                for (int j = 0; j < 8; ++j) {
                    float hv = reinterpret_cast<const float*>(&h4[j])[kk];
                    acc[j][0] = fmaf(hv, w4.x, acc[j][0]);
                    acc[j][1] = fmaf(hv, w4.y, acc[j][1]);
                    acc[j][2] = fmaf(hv, w4.z, acc[j][2]);
                    acc[j][3] = fmaf(hv, w4.w, acc[j][3]);
                }
            }
        }
        __syncthreads();
    }
    #pragma unroll
    for (int j = 0; j < 8; ++j) {
        int gr = row0 + ro * 8 + j;
        if (gr < N) {
            *reinterpret_cast<float4*>(y + (size_t)gr * F + co * 4) =
                make_float4(acc[j][0], acc[j][1], acc[j][2], acc[j][3]);
        }
    }
}

// ---------------- BatchNorm ----------------
__global__ __launch_bounds__(256) void k_stats(
        const float* __restrict__ y, float* __restrict__ colsum,
        float* __restrict__ colsumsq, int N) {
    __shared__ float ls[256], lss[256];
    int t = threadIdx.x;
    int col = t & 127, half = t >> 7;
    float s = 0.f, ss = 0.f;
    for (int r = blockIdx.x * 2 + half; r < N; r += gridDim.x * 2) {
        float v = y[(size_t)r * F + col];
        s += v; ss += v * v;
    }
    ls[t] = s; lss[t] = ss;
    __syncthreads();
    if (t < 128) {
        atomicAdd(&colsum[col], ls[t] + ls[t + 128]);
        atomicAdd(&colsumsq[col], lss[t] + lss[t + 128]);
    }
}

__global__ void k_finalize(const float* __restrict__ colsum,
                           const float* __restrict__ colsumsq,
                           const float* __restrict__ gamma,
                           const float* __restrict__ beta,
                           float* __restrict__ scaleshift, float ninv) {
    int o = threadIdx.x;
    float mean = colsum[o] * ninv;
    float var = colsumsq[o] * ninv - mean * mean;
    float rstd = rsqrtf(var + EPSV);
    float sc = gamma[o] * rstd;
    scaleshift[o] = sc;
    scaleshift[F + o] = beta[o] - mean * sc;
}

__global__ __launch_bounds__(256) void k_norm(
        float* __restrict__ y, const float* __restrict__ scaleshift,
        int total4) {
    int idx = blockIdx.x * 256 + threadIdx.x;
    if (idx >= total4) return;
    int col4 = (idx & 31) * 4;
    float4 v = *reinterpret_cast<const float4*>(y + (size_t)idx * 4);
    float4 o4;
    o4.x = v.x * scaleshift[col4 + 0] + scaleshift[F + col4 + 0];
    o4.y = v.y * scaleshift[col4 + 1] + scaleshift[F + col4 + 1];
    o4.z = v.z * scaleshift[col4 + 2] + scaleshift[F + col4 + 2];
    o4.w = v.w * scaleshift[col4 + 3] + scaleshift[F + col4 + 3];
    *reinterpret_cast<float4*>(y + (size_t)idx * 4) = o4;
}

extern "C" void kernel_launch(void* const* d_in, const int* in_sizes, int n_in,
                              void* d_out, int out_size, void* d_ws, size_t ws_size,
                              hipStream_t stream) {
    (void)n_in; (void)out_size;
    const float* x     = (const float*)d_in[0];
    const int*   src   = (const int*)d_in[1];
    const int*   dst   = (const int*)d_in[2];
    const float* we    = (const float*)d_in[3];
    const float* W     = (const float*)d_in[4];
    const float* gamma = (const float*)d_in[5];
    const float* beta  = (const float*)d_in[6];
    int N = in_sizes[0] / F;
    int E = in_sizes[1];

    char* ws = (char*)d_ws;
    size_t off = 0;
    auto alloc = [&](size_t bytes) {
        void* p = ws + off;
        off += (bytes + 255) & ~(size_t)255;
        return p;
    };
    float* agg        = (float*)alloc((size_t)N * F * sizeof(float));
    float* colsum     = (float*)alloc(F * sizeof(float));
    float* colsumsq   = (float*)alloc(F * sizeof(float));
    float* scaleshift = (float*)alloc(2 * F * sizeof(float));
    int*   counts     = (int*)alloc((size_t)N * sizeof(int));
    int*   rowptr     = (int*)alloc((size_t)N * sizeof(int));
    int*   cursor     = (int*)alloc((size_t)N * sizeof(int));
    int*   partials   = (int*)alloc(1024 * sizeof(int));
    int*   esrc       = (int*)alloc((size_t)E * sizeof(int));
    float* ewbuf      = (float*)alloc((size_t)E * sizeof(float));
    bool csr_ok = (off <= ws_size);

    float* y = (float*)d_out;

    hipMemsetAsync(colsum, 0, 2 * F * sizeof(float), stream);

    if (csr_ok) {
        int nchunks = (N + 1023) / 1024;
        hipMemsetAsync(counts, 0, (size_t)N * sizeof(int), stream);
        hipLaunchKernelGGL(k_hist, dim3((E + 255) / 256), dim3(256), 0, stream,
                           dst, counts, E);
        hipLaunchKernelGGL(k_scan1, dim3(nchunks), dim3(256), 0, stream,
                           counts, rowptr, partials, N);
        hipLaunchKernelGGL(k_scan2, dim3(1), dim3(64), 0, stream,
                           partials, nchunks);
        hipLaunchKernelGGL(k_scan3, dim3((N + 255) / 256), dim3(256), 0, stream,
                           rowptr, cursor, partials, N);
        hipLaunchKernelGGL(k_fill, dim3((E + 255) / 256), dim3(256), 0, stream,
                           src, dst, we, cursor, esrc, ewbuf, E);
        hipLaunchKernelGGL(k_agg, dim3((N + 3) / 4), dim3(256), 0, stream,
                           x, rowptr, counts, esrc, ewbuf, agg, N);
    } else {
        hipMemsetAsync(agg, 0, (size_t)N * F * sizeof(float), stream);
        hipLaunchKernelGGL(k_scatter, dim3((E * 32 + 255) / 256), dim3(256), 0, stream,
                           x, src, dst, we, agg, E);
    }

    hipLaunchKernelGGL(k_gemm, dim3((N + BM - 1) / BM), dim3(256), 0, stream,
                       x, agg, W, y, N);
    hipLaunchKernelGGL(k_stats, dim3(256), dim3(256), 0, stream,
                       y, colsum, colsumsq, N);
    hipLaunchKernelGGL(k_finalize, dim3(1), dim3(F), 0, stream,
                       colsum, colsumsq, gamma, beta, scaleshift, 1.0f / (float)N);
    hipLaunchKernelGGL(k_norm, dim3((N * 32 + 255) / 256), dim3(256), 0, stream,
                       y, scaleshift, N * 32);
}

// Round 4
// 227.950 us; speedup vs baseline: 6.7469x; 1.5398x over previous
//
#include <hip/hip_runtime.h>

#define F 128            // F_IN == F_OUT == 128
#define EPSV 1e-5f

typedef _Float16 f16x8 __attribute__((ext_vector_type(8)));
typedef _Float16 f16x4 __attribute__((ext_vector_type(4)));
typedef _Float16 f16x2 __attribute__((ext_vector_type(2)));
typedef float    f32x4 __attribute__((ext_vector_type(4)));

// ---------------- f32 -> f16 conversion (x and W) ----------------
__global__ __launch_bounds__(256) void k_cvt(
        const float* __restrict__ in, _Float16* __restrict__ out, int n4) {
    int i = blockIdx.x * 256 + threadIdx.x;
    if (i >= n4) return;
    float4 v = *reinterpret_cast<const float4*>(in + (size_t)i * 4);
    f16x4 o = { (_Float16)v.x, (_Float16)v.y, (_Float16)v.z, (_Float16)v.w };
    *reinterpret_cast<f16x4*>(out + (size_t)i * 4) = o;
}

// ---------------- CSR build ----------------
__global__ __launch_bounds__(256) void k_hist(
        const int* __restrict__ dst, int* __restrict__ counts, int E) {
    int e = blockIdx.x * 256 + threadIdx.x;
    if (e < E) atomicAdd(&counts[dst[e]], 1);
}

__global__ __launch_bounds__(256) void k_scan1(
        const int* __restrict__ counts, int* __restrict__ rowptr,
        int* __restrict__ partials, int N) {
    __shared__ int wsum[4];
    int t = threadIdx.x;
    int base = blockIdx.x * 1024;
    int lane = t & 63, wv = t >> 6;
    int v[4], s = 0;
    #pragma unroll
    for (int i = 0; i < 4; ++i) {
        int idx = base + t * 4 + i;
        v[i] = (idx < N) ? counts[idx] : 0;
        s += v[i];
    }
    int sc = s;
    #pragma unroll
    for (int off = 1; off < 64; off <<= 1) {
        int o = __shfl_up(sc, off);
        if (lane >= off) sc += o;
    }
    if (lane == 63) wsum[wv] = sc;
    __syncthreads();
    int woff = 0;
    for (int i = 0; i < wv; ++i) woff += wsum[i];
    int excl = woff + sc - s;
    #pragma unroll
    for (int i = 0; i < 4; ++i) {
        int idx = base + t * 4 + i;
        if (idx < N) rowptr[idx] = excl;
        excl += v[i];
    }
    if (t == 255) partials[blockIdx.x] = woff + sc;
}

__global__ void k_scan2(int* __restrict__ partials, int nb) {
    int t = threadIdx.x;  // 64 threads
    int carry = 0;
    for (int b = 0; b < nb; b += 64) {
        int i = b + t;
        int v = (i < nb) ? partials[i] : 0;
        int sc = v;
        #pragma unroll
        for (int off = 1; off < 64; off <<= 1) {
            int o = __shfl_up(sc, off);
            if (t >= off) sc += o;
        }
        if (i < nb) partials[i] = carry + sc - v;
        carry += __shfl(sc, 63);
    }
}

__global__ __launch_bounds__(256) void k_scan3(
        int* __restrict__ rowptr, int* __restrict__ cursor,
        const int* __restrict__ partials, int N) {
    int idx = blockIdx.x * 256 + threadIdx.x;
    if (idx >= N) return;
    int r = rowptr[idx] + partials[idx >> 10];
    rowptr[idx] = r;
    cursor[idx] = r;
}

__global__ __launch_bounds__(256) void k_fill(
        const int* __restrict__ src, const int* __restrict__ dst,
        const float* __restrict__ we, int* __restrict__ cursor,
        int* __restrict__ esrc, float* __restrict__ ew, int E) {
    int e = blockIdx.x * 256 + threadIdx.x;
    if (e >= E) return;
    int d = dst[e];
    int slot = atomicAdd(&cursor[d], 1);
    esrc[slot] = src[e];
    ew[slot]   = we[e];
}

// A1: pull-mode aggregation from f16 x; one wave per node, f16x2 per lane.
__global__ __launch_bounds__(256) void k_agg(
        const _Float16* __restrict__ xh, const int* __restrict__ rowptr,
        const int* __restrict__ counts, const int* __restrict__ esrc,
        const float* __restrict__ ew, _Float16* __restrict__ aggh, int N) {
    int wv = threadIdx.x >> 6, lane = threadIdx.x & 63;
    int n = blockIdx.x * 4 + wv;
    if (n >= N) return;
    int beg = rowptr[n], cnt = counts[n];
    float ax = 0.f, ay = 0.f;
    int i = 0;
    for (; i + 2 <= cnt; i += 2) {
        int   s0 = esrc[beg + i],  s1 = esrc[beg + i + 1];
        float w0 = ew[beg + i],    w1 = ew[beg + i + 1];
        f16x2 v0 = *reinterpret_cast<const f16x2*>(xh + (size_t)s0 * F + lane * 2);
        f16x2 v1 = *reinterpret_cast<const f16x2*>(xh + (size_t)s1 * F + lane * 2);
        ax += w0 * (float)v0[0] + w1 * (float)v1[0];
        ay += w0 * (float)v0[1] + w1 * (float)v1[1];
    }
    if (i < cnt) {
        int   s0 = esrc[beg + i];
        float w0 = ew[beg + i];
        f16x2 v0 = *reinterpret_cast<const f16x2*>(xh + (size_t)s0 * F + lane * 2);
        ax += w0 * (float)v0[0];
        ay += w0 * (float)v0[1];
    }
    f16x2 o = { (_Float16)ax, (_Float16)ay };
    *reinterpret_cast<f16x2*>(aggh + (size_t)n * F + lane * 2) = o;
}

// ---------------- MFMA GEMM: y = [x, agg] @ W^T, fused column stats ----------
// Block = 256 threads = 4 waves. Wave w: rows rows0..rows0+15 (16 rows),
// loops 8 col-tiles of 16 cols. K = 256 in 8 steps of 32.
// A-frag: lane l holds h[rows0+(l&15)][k0+(l>>4)*8 + 0..7]   (16B global load)
// B-frag: lane l holds W[ct*16+(l&15)][k0+(l>>4)*8 + 0..7]   (16B global load)
// D: acc[ct][r] = y[rows0+(l>>4)*4+r][ct*16+(l&15)]
__global__ __launch_bounds__(256) void k_gemm_mfma(
        const _Float16* __restrict__ xh, const _Float16* __restrict__ aggh,
        const _Float16* __restrict__ wh, float* __restrict__ y,
        float* __restrict__ colsum, float* __restrict__ colsumsq, int N) {
    __shared__ float lds_s[4][128], lds_q[4][128];
    int t = threadIdx.x, w = t >> 6, l = t & 63;
    int lo16 = l & 15, hi4 = l >> 4;
    int rows0 = blockIdx.x * 64 + w * 16;
    int row_a = rows0 + lo16;
    if (row_a >= N) row_a = N - 1;          // clamp; results discarded below

    f32x4 acc[8] = {};
    const _Float16* wbase = wh + (size_t)lo16 * 256 + hi4 * 8;
    #pragma unroll
    for (int kb = 0; kb < 8; ++kb) {
        const _Float16* ap = (kb < 4)
            ? (xh   + (size_t)row_a * F + kb * 32 + hi4 * 8)
            : (aggh + (size_t)row_a * F + (kb - 4) * 32 + hi4 * 8);
        f16x8 afrag = *reinterpret_cast<const f16x8*>(ap);
        #pragma unroll
        for (int ct = 0; ct < 8; ++ct) {
            f16x8 bfrag = *reinterpret_cast<const f16x8*>(
                wbase + (size_t)ct * 16 * 256 + kb * 32);
            acc[ct] = __builtin_amdgcn_mfma_f32_16x16x32_f16(
                afrag, bfrag, acc[ct], 0, 0, 0);
        }
    }

    // epilogue: write y, reduce column sum/sumsq
    #pragma unroll
    for (int ct = 0; ct < 8; ++ct) {
        float sv = 0.f, qv = 0.f;
        int col = ct * 16 + lo16;
        #pragma unroll
        for (int r = 0; r < 4; ++r) {
            int row = rows0 + hi4 * 4 + r;
            float v = acc[ct][r];
            if (row < N) {
                y[(size_t)row * F + col] = v;
                sv += v;
                qv += v * v;
            }
        }
        sv += __shfl_xor(sv, 16); sv += __shfl_xor(sv, 32);
        qv += __shfl_xor(qv, 16); qv += __shfl_xor(qv, 32);
        if (l < 16) {
            lds_s[w][ct * 16 + l] = sv;
            lds_q[w][ct * 16 + l] = qv;
        }
    }
    __syncthreads();
    if (t < 128) {
        float S = lds_s[0][t] + lds_s[1][t] + lds_s[2][t] + lds_s[3][t];
        float Q = lds_q[0][t] + lds_q[1][t] + lds_q[2][t] + lds_q[3][t];
        atomicAdd(&colsum[t], S);
        atomicAdd(&colsumsq[t], Q);
    }
}

// ---------------- BatchNorm finalize + normalize ----------------
__global__ void k_finalize(const float* __restrict__ colsum,
                           const float* __restrict__ colsumsq,
                           const float* __restrict__ gamma,
                           const float* __restrict__ beta,
                           float* __restrict__ scaleshift, float ninv) {
    int o = threadIdx.x;
    float mean = colsum[o] * ninv;
    float var = colsumsq[o] * ninv - mean * mean;
    float rstd = rsqrtf(var + EPSV);
    float sc = gamma[o] * rstd;
    scaleshift[o] = sc;
    scaleshift[F + o] = beta[o] - mean * sc;
}

__global__ __launch_bounds__(256) void k_norm(
        float* __restrict__ y, const float* __restrict__ scaleshift,
        int total4) {
    int idx = blockIdx.x * 256 + threadIdx.x;
    if (idx >= total4) return;
    int col4 = (idx & 31) * 4;
    float4 v = *reinterpret_cast<const float4*>(y + (size_t)idx * 4);
    float4 o4;
    o4.x = v.x * scaleshift[col4 + 0] + scaleshift[F + col4 + 0];
    o4.y = v.y * scaleshift[col4 + 1] + scaleshift[F + col4 + 1];
    o4.z = v.z * scaleshift[col4 + 2] + scaleshift[F + col4 + 2];
    o4.w = v.w * scaleshift[col4 + 3] + scaleshift[F + col4 + 3];
    *reinterpret_cast<float4*>(y + (size_t)idx * 4) = o4;
}

extern "C" void kernel_launch(void* const* d_in, const int* in_sizes, int n_in,
                              void* d_out, int out_size, void* d_ws, size_t ws_size,
                              hipStream_t stream) {
    (void)n_in; (void)out_size; (void)ws_size;
    const float* x     = (const float*)d_in[0];
    const int*   src   = (const int*)d_in[1];
    const int*   dst   = (const int*)d_in[2];
    const float* we    = (const float*)d_in[3];
    const float* W     = (const float*)d_in[4];
    const float* gamma = (const float*)d_in[5];
    const float* beta  = (const float*)d_in[6];
    int N = in_sizes[0] / F;
    int E = in_sizes[1];

    char* ws = (char*)d_ws;
    size_t off = 0;
    auto alloc = [&](size_t bytes) {
        void* p = ws + off;
        off += (bytes + 255) & ~(size_t)255;
        return p;
    };
    _Float16* xh     = (_Float16*)alloc((size_t)N * F * sizeof(_Float16));
    _Float16* aggh   = (_Float16*)alloc((size_t)N * F * sizeof(_Float16));
    _Float16* wh     = (_Float16*)alloc((size_t)F * 2 * F * sizeof(_Float16));
    float* stats     = (float*)alloc(4 * F * sizeof(float));  // colsum|colsumsq|scaleshift(2F)
    int*   counts    = (int*)alloc((size_t)N * sizeof(int));
    int*   rowptr    = (int*)alloc((size_t)N * sizeof(int));
    int*   cursor    = (int*)alloc((size_t)N * sizeof(int));
    int*   partials  = (int*)alloc(1024 * sizeof(int));
    int*   esrc      = (int*)alloc((size_t)E * sizeof(int));
    float* ewbuf     = (float*)alloc((size_t)E * sizeof(float));
    float* colsum     = stats;
    float* colsumsq   = stats + F;
    float* scaleshift = stats + 2 * F;

    float* y = (float*)d_out;

    hipMemsetAsync(stats, 0, 2 * F * sizeof(float), stream);
    hipMemsetAsync(counts, 0, (size_t)N * sizeof(int), stream);

    // conversions
    hipLaunchKernelGGL(k_cvt, dim3((N * F / 4 + 255) / 256), dim3(256), 0, stream,
                       x, xh, N * F / 4);
    hipLaunchKernelGGL(k_cvt, dim3((2 * F * F / 4 + 255) / 256), dim3(256), 0, stream,
                       W, wh, 2 * F * F / 4);

    // CSR build
    int nchunks = (N + 1023) / 1024;
    hipLaunchKernelGGL(k_hist, dim3((E + 255) / 256), dim3(256), 0, stream,
                       dst, counts, E);
    hipLaunchKernelGGL(k_scan1, dim3(nchunks), dim3(256), 0, stream,
                       counts, rowptr, partials, N);
    hipLaunchKernelGGL(k_scan2, dim3(1), dim3(64), 0, stream,
                       partials, nchunks);
    hipLaunchKernelGGL(k_scan3, dim3((N + 255) / 256), dim3(256), 0, stream,
                       rowptr, cursor, partials, N);
    hipLaunchKernelGGL(k_fill, dim3((E + 255) / 256), dim3(256), 0, stream,
                       src, dst, we, cursor, esrc, ewbuf, E);

    // aggregation (pull)
    hipLaunchKernelGGL(k_agg, dim3((N + 3) / 4), dim3(256), 0, stream,
                       xh, rowptr, counts, esrc, ewbuf, aggh, N);

    // MFMA GEMM + fused stats
    hipLaunchKernelGGL(k_gemm_mfma, dim3((N + 63) / 64), dim3(256), 0, stream,
                       xh, aggh, wh, y, colsum, colsumsq, N);

    // BN finalize + normalize in place
    hipLaunchKernelGGL(k_finalize, dim3(1), dim3(F), 0, stream,
                       colsum, colsumsq, gamma, beta, scaleshift, 1.0f / (float)N);
    hipLaunchKernelGGL(k_norm, dim3((N * 32 + 255) / 256), dim3(256), 0, stream,
                       y, scaleshift, N * 32);
}

// Round 5
// 205.821 us; speedup vs baseline: 7.4723x; 1.1075x over previous
//
#include <hip/hip_runtime.h>

#define F 128            // F_IN == F_OUT == 128
#define EPSV 1e-5f

typedef _Float16 f16x8 __attribute__((ext_vector_type(8)));
typedef _Float16 f16x4 __attribute__((ext_vector_type(4)));
typedef _Float16 f16x2 __attribute__((ext_vector_type(2)));
typedef float    f32x4 __attribute__((ext_vector_type(4)));

// ---------------- f32 -> f16 conversion (x and W) ----------------
__global__ __launch_bounds__(256) void k_cvt(
        const float* __restrict__ in, _Float16* __restrict__ out, int n4) {
    int i = blockIdx.x * 256 + threadIdx.x;
    if (i >= n4) return;
    float4 v = *reinterpret_cast<const float4*>(in + (size_t)i * 4);
    f16x4 o = { (_Float16)v.x, (_Float16)v.y, (_Float16)v.z, (_Float16)v.w };
    *reinterpret_cast<f16x4*>(out + (size_t)i * 4) = o;
}

// ---------------- CSR build ----------------

// H1: histogram of dst; atomic return value = stable rank within bucket
__global__ __launch_bounds__(256) void k_hist(
        const int* __restrict__ dst, int* __restrict__ counts,
        int* __restrict__ rank, int E) {
    int e = blockIdx.x * 256 + threadIdx.x;
    if (e < E) rank[e] = atomicAdd(&counts[dst[e]], 1);
}

// S1: per-chunk (1024 elems) exclusive scan; chunk totals -> partials
__global__ __launch_bounds__(256) void k_scan1(
        const int* __restrict__ counts, int* __restrict__ rowptr,
        int* __restrict__ partials, int N) {
    __shared__ int wsum[4];
    int t = threadIdx.x;
    int base = blockIdx.x * 1024;
    int lane = t & 63, wv = t >> 6;
    int v[4], s = 0;
    #pragma unroll
    for (int i = 0; i < 4; ++i) {
        int idx = base + t * 4 + i;
        v[i] = (idx < N) ? counts[idx] : 0;
        s += v[i];
    }
    int sc = s;
    #pragma unroll
    for (int off = 1; off < 64; off <<= 1) {
        int o = __shfl_up(sc, off);
        if (lane >= off) sc += o;
    }
    if (lane == 63) wsum[wv] = sc;
    __syncthreads();
    int woff = 0;
    for (int i = 0; i < wv; ++i) woff += wsum[i];
    int excl = woff + sc - s;
    #pragma unroll
    for (int i = 0; i < 4; ++i) {
        int idx = base + t * 4 + i;
        if (idx < N) rowptr[idx] = excl;
        excl += v[i];
    }
    if (t == 255) partials[blockIdx.x] = woff + sc;
}

// S2: exclusive scan of chunk totals (single wave, generic nb)
__global__ void k_scan2(int* __restrict__ partials, int nb) {
    int t = threadIdx.x;  // 64 threads
    int carry = 0;
    for (int b = 0; b < nb; b += 64) {
        int i = b + t;
        int v = (i < nb) ? partials[i] : 0;
        int sc = v;
        #pragma unroll
        for (int off = 1; off < 64; off <<= 1) {
            int o = __shfl_up(sc, off);
            if (t >= off) sc += o;
        }
        if (i < nb) partials[i] = carry + sc - v;
        carry += __shfl(sc, 63);
    }
}

// F1: scatter edge id into its CSR slot (no atomics; one 4B store per edge)
__global__ __launch_bounds__(256) void k_fill(
        const int* __restrict__ dst, const int* __restrict__ rank,
        const int* __restrict__ rowptr, const int* __restrict__ partials,
        int* __restrict__ eslot, int E) {
    int e = blockIdx.x * 256 + threadIdx.x;
    if (e >= E) return;
    int d = dst[e];
    int slot = rowptr[d] + partials[d >> 10] + rank[e];
    eslot[slot] = e;
}

// A1: pull-mode aggregation from f16 x; one wave per node, f16x2 per lane.
__global__ __launch_bounds__(256) void k_agg(
        const _Float16* __restrict__ xh, const int* __restrict__ rowptr,
        const int* __restrict__ partials, const int* __restrict__ counts,
        const int* __restrict__ eslot,
        const int* __restrict__ src, const float* __restrict__ we,
        _Float16* __restrict__ aggh, int N) {
    int wv = threadIdx.x >> 6, lane = threadIdx.x & 63;
    int n = blockIdx.x * 4 + wv;
    if (n >= N) return;
    int beg = rowptr[n] + partials[n >> 10];
    int cnt = counts[n];
    float ax = 0.f, ay = 0.f;
    int i = 0;
    for (; i + 2 <= cnt; i += 2) {
        int   e0 = eslot[beg + i],  e1 = eslot[beg + i + 1];
        int   s0 = src[e0],         s1 = src[e1];
        float w0 = we[e0],          w1 = we[e1];
        f16x2 v0 = *reinterpret_cast<const f16x2*>(xh + (size_t)s0 * F + lane * 2);
        f16x2 v1 = *reinterpret_cast<const f16x2*>(xh + (size_t)s1 * F + lane * 2);
        ax += w0 * (float)v0[0] + w1 * (float)v1[0];
        ay += w0 * (float)v0[1] + w1 * (float)v1[1];
    }
    if (i < cnt) {
        int   e0 = eslot[beg + i];
        int   s0 = src[e0];
        float w0 = we[e0];
        f16x2 v0 = *reinterpret_cast<const f16x2*>(xh + (size_t)s0 * F + lane * 2);
        ax += w0 * (float)v0[0];
        ay += w0 * (float)v0[1];
    }
    f16x2 o = { (_Float16)ax, (_Float16)ay };
    *reinterpret_cast<f16x2*>(aggh + (size_t)n * F + lane * 2) = o;
}

// ---------------- MFMA GEMM: y = [x, agg] @ W^T, fused column stats ----------
__global__ __launch_bounds__(256) void k_gemm_mfma(
        const _Float16* __restrict__ xh, const _Float16* __restrict__ aggh,
        const _Float16* __restrict__ wh, float* __restrict__ y,
        float* __restrict__ colsum, float* __restrict__ colsumsq, int N) {
    __shared__ float lds_s[4][128], lds_q[4][128];
    int t = threadIdx.x, w = t >> 6, l = t & 63;
    int lo16 = l & 15, hi4 = l >> 4;
    int rows0 = blockIdx.x * 64 + w * 16;
    int row_a = rows0 + lo16;
    if (row_a >= N) row_a = N - 1;          // clamp; results discarded below

    f32x4 acc[8] = {};
    const _Float16* wbase = wh + (size_t)lo16 * 256 + hi4 * 8;
    #pragma unroll
    for (int kb = 0; kb < 8; ++kb) {
        const _Float16* ap = (kb < 4)
            ? (xh   + (size_t)row_a * F + kb * 32 + hi4 * 8)
            : (aggh + (size_t)row_a * F + (kb - 4) * 32 + hi4 * 8);
        f16x8 afrag = *reinterpret_cast<const f16x8*>(ap);
        #pragma unroll
        for (int ct = 0; ct < 8; ++ct) {
            f16x8 bfrag = *reinterpret_cast<const f16x8*>(
                wbase + (size_t)ct * 16 * 256 + kb * 32);
            acc[ct] = __builtin_amdgcn_mfma_f32_16x16x32_f16(
                afrag, bfrag, acc[ct], 0, 0, 0);
        }
    }

    #pragma unroll
    for (int ct = 0; ct < 8; ++ct) {
        float sv = 0.f, qv = 0.f;
        int col = ct * 16 + lo16;
        #pragma unroll
        for (int r = 0; r < 4; ++r) {
            int row = rows0 + hi4 * 4 + r;
            float v = acc[ct][r];
            if (row < N) {
                y[(size_t)row * F + col] = v;
                sv += v;
                qv += v * v;
            }
        }
        sv += __shfl_xor(sv, 16); sv += __shfl_xor(sv, 32);
        qv += __shfl_xor(qv, 16); qv += __shfl_xor(qv, 32);
        if (l < 16) {
            lds_s[w][ct * 16 + l] = sv;
            lds_q[w][ct * 16 + l] = qv;
        }
    }
    __syncthreads();
    if (t < 128) {
        float S = lds_s[0][t] + lds_s[1][t] + lds_s[2][t] + lds_s[3][t];
        float Q = lds_q[0][t] + lds_q[1][t] + lds_q[2][t] + lds_q[3][t];
        atomicAdd(&colsum[t], S);
        atomicAdd(&colsumsq[t], Q);
    }
}

// ---------------- BatchNorm: finalize folded into normalize ----------------
__global__ __launch_bounds__(256) void k_norm(
        float* __restrict__ y, const float* __restrict__ colsum,
        const float* __restrict__ colsumsq, const float* __restrict__ gamma,
        const float* __restrict__ beta, float ninv, int total4) {
    __shared__ float sc_sh[F], sh_sh[F];
    int t = threadIdx.x;
    if (t < F) {
        float mean = colsum[t] * ninv;
        float var = colsumsq[t] * ninv - mean * mean;
        float rstd = rsqrtf(var + EPSV);
        float sc = gamma[t] * rstd;
        sc_sh[t] = sc;
        sh_sh[t] = beta[t] - mean * sc;
    }
    __syncthreads();
    int idx = blockIdx.x * 256 + t;
    if (idx >= total4) return;
    int col4 = (idx & 31) * 4;
    float4 v = *reinterpret_cast<const float4*>(y + (size_t)idx * 4);
    float4 o4;
    o4.x = v.x * sc_sh[col4 + 0] + sh_sh[col4 + 0];
    o4.y = v.y * sc_sh[col4 + 1] + sh_sh[col4 + 1];
    o4.z = v.z * sc_sh[col4 + 2] + sh_sh[col4 + 2];
    o4.w = v.w * sc_sh[col4 + 3] + sh_sh[col4 + 3];
    *reinterpret_cast<float4*>(y + (size_t)idx * 4) = o4;
}

extern "C" void kernel_launch(void* const* d_in, const int* in_sizes, int n_in,
                              void* d_out, int out_size, void* d_ws, size_t ws_size,
                              hipStream_t stream) {
    (void)n_in; (void)out_size; (void)ws_size;
    const float* x     = (const float*)d_in[0];
    const int*   src   = (const int*)d_in[1];
    const int*   dst   = (const int*)d_in[2];
    const float* we    = (const float*)d_in[3];
    const float* W     = (const float*)d_in[4];
    const float* gamma = (const float*)d_in[5];
    const float* beta  = (const float*)d_in[6];
    int N = in_sizes[0] / F;
    int E = in_sizes[1];

    char* ws = (char*)d_ws;
    size_t off = 0;
    auto alloc = [&](size_t bytes) {
        void* p = ws + off;
        off += (bytes + 255) & ~(size_t)255;
        return p;
    };
    _Float16* xh     = (_Float16*)alloc((size_t)N * F * sizeof(_Float16));
    _Float16* aggh   = (_Float16*)alloc((size_t)N * F * sizeof(_Float16));
    _Float16* wh     = (_Float16*)alloc((size_t)F * 2 * F * sizeof(_Float16));
    float* stats     = (float*)alloc(2 * F * sizeof(float));   // colsum | colsumsq
    int*   counts    = (int*)alloc((size_t)N * sizeof(int));
    int*   rowptr    = (int*)alloc((size_t)N * sizeof(int));
    int*   partials  = (int*)alloc(1024 * sizeof(int));
    int*   rank      = (int*)alloc((size_t)E * sizeof(int));
    int*   eslot     = (int*)alloc((size_t)E * sizeof(int));
    float* colsum    = stats;
    float* colsumsq  = stats + F;

    float* y = (float*)d_out;

    hipMemsetAsync(stats, 0, 2 * F * sizeof(float), stream);
    hipMemsetAsync(counts, 0, (size_t)N * sizeof(int), stream);

    // conversions
    hipLaunchKernelGGL(k_cvt, dim3((N * F / 4 + 255) / 256), dim3(256), 0, stream,
                       x, xh, N * F / 4);
    hipLaunchKernelGGL(k_cvt, dim3((2 * F * F / 4 + 255) / 256), dim3(256), 0, stream,
                       W, wh, 2 * F * F / 4);

    // CSR build (rank from histogram; no cursor atomics)
    int nchunks = (N + 1023) / 1024;
    hipLaunchKernelGGL(k_hist, dim3((E + 255) / 256), dim3(256), 0, stream,
                       dst, counts, rank, E);
    hipLaunchKernelGGL(k_scan1, dim3(nchunks), dim3(256), 0, stream,
                       counts, rowptr, partials, N);
    hipLaunchKernelGGL(k_scan2, dim3(1), dim3(64), 0, stream,
                       partials, nchunks);
    hipLaunchKernelGGL(k_fill, dim3((E + 255) / 256), dim3(256), 0, stream,
                       dst, rank, rowptr, partials, eslot, E);

    // aggregation (pull, eid-indirect)
    hipLaunchKernelGGL(k_agg, dim3((N + 3) / 4), dim3(256), 0, stream,
                       xh, rowptr, partials, counts, eslot, src, we, aggh, N);

    // MFMA GEMM + fused stats
    hipLaunchKernelGGL(k_gemm_mfma, dim3((N + 63) / 64), dim3(256), 0, stream,
                       xh, aggh, wh, y, colsum, colsumsq, N);

    // BN finalize + normalize in place
    hipLaunchKernelGGL(k_norm, dim3((N * 32 + 255) / 256), dim3(256), 0, stream,
                       y, colsum, colsumsq, gamma, beta, 1.0f / (float)N, N * 32);
}

// Round 6
// 168.960 us; speedup vs baseline: 9.1025x; 1.2182x over previous
//
#include <hip/hip_runtime.h>

#define F 128            // F_IN == F_OUT == 128
#define EPSV 1e-5f

typedef _Float16 f16x8 __attribute__((ext_vector_type(8)));
typedef _Float16 f16x4 __attribute__((ext_vector_type(4)));
typedef _Float16 f16x2 __attribute__((ext_vector_type(2)));
typedef float    f32x4 __attribute__((ext_vector_type(4)));

// ---------------- x f32->f16 + zero counts ----------------
__global__ __launch_bounds__(256) void k_cvt_x(
        const float* __restrict__ in, _Float16* __restrict__ out, int n4,
        int* __restrict__ counts, int ncnt4) {
    int i = blockIdx.x * 256 + threadIdx.x;
    if (i < ncnt4)  // counts alloc is 256B-padded; int4 overshoot is safe
        *reinterpret_cast<int4*>(counts + i * 4) = make_int4(0, 0, 0, 0);
    if (i >= n4) return;
    float4 v = *reinterpret_cast<const float4*>(in + (size_t)i * 4);
    f16x4 o = { (_Float16)v.x, (_Float16)v.y, (_Float16)v.z, (_Float16)v.w };
    *reinterpret_cast<f16x4*>(out + (size_t)i * 4) = o;
}

// ---------------- W f32->f16 ----------------
__global__ __launch_bounds__(256) void k_cvt_w(
        const float* __restrict__ in, _Float16* __restrict__ out, int n4) {
    int i = blockIdx.x * 256 + threadIdx.x;
    if (i >= n4) return;
    float4 v = *reinterpret_cast<const float4*>(in + (size_t)i * 4);
    f16x4 o = { (_Float16)v.x, (_Float16)v.y, (_Float16)v.z, (_Float16)v.w };
    *reinterpret_cast<f16x4*>(out + (size_t)i * 4) = o;
}

// ---------------- CSR build ----------------

// H1: histogram of dst; atomic return value = rank within bucket
__global__ __launch_bounds__(256) void k_hist(
        const int* __restrict__ dst, int* __restrict__ counts,
        int* __restrict__ rank, int E) {
    int e = blockIdx.x * 256 + threadIdx.x;
    if (e < E) rank[e] = atomicAdd(&counts[dst[e]], 1);
}

// S1: per-chunk (1024 elems) exclusive scan; chunk totals -> partials
__global__ __launch_bounds__(256) void k_scan1(
        const int* __restrict__ counts, int* __restrict__ rowptr,
        int* __restrict__ partials, int N) {
    __shared__ int wsum[4];
    int t = threadIdx.x;
    int base = blockIdx.x * 1024;
    int lane = t & 63, wv = t >> 6;
    int v[4], s = 0;
    #pragma unroll
    for (int i = 0; i < 4; ++i) {
        int idx = base + t * 4 + i;
        v[i] = (idx < N) ? counts[idx] : 0;
        s += v[i];
    }
    int sc = s;
    #pragma unroll
    for (int off = 1; off < 64; off <<= 1) {
        int o = __shfl_up(sc, off);
        if (lane >= off) sc += o;
    }
    if (lane == 63) wsum[wv] = sc;
    __syncthreads();
    int woff = 0;
    for (int i = 0; i < wv; ++i) woff += wsum[i];
    int excl = woff + sc - s;
    #pragma unroll
    for (int i = 0; i < 4; ++i) {
        int idx = base + t * 4 + i;
        if (idx < N) rowptr[idx] = excl;
        excl += v[i];
    }
    if (t == 255) partials[blockIdx.x] = woff + sc;
}

// S2: exclusive scan of chunk totals + zero BN stats (256 floats)
__global__ void k_scan2(int* __restrict__ partials, int nb,
                        float* __restrict__ stats) {
    int t = threadIdx.x;  // 64 threads
    *reinterpret_cast<float4*>(stats + t * 4) = make_float4(0.f, 0.f, 0.f, 0.f);
    int carry = 0;
    for (int b = 0; b < nb; b += 64) {
        int i = b + t;
        int v = (i < nb) ? partials[i] : 0;
        int sc = v;
        #pragma unroll
        for (int off = 1; off < 64; off <<= 1) {
            int o = __shfl_up(sc, off);
            if (t >= off) sc += o;
        }
        if (i < nb) partials[i] = carry + sc - v;
        carry += __shfl(sc, 63);
    }
}

// F1: scatter packed {src, w} payload into CSR slot (no atomics)
__global__ __launch_bounds__(256) void k_fill(
        const int* __restrict__ dst, const int* __restrict__ rank,
        const int* __restrict__ rowptr, const int* __restrict__ partials,
        const int* __restrict__ src, const float* __restrict__ we,
        int2* __restrict__ payload, int E) {
    int e = blockIdx.x * 256 + threadIdx.x;
    if (e >= E) return;
    int d = dst[e];
    int slot = rowptr[d] + partials[d >> 10] + rank[e];
    payload[slot] = make_int2(src[e], __float_as_int(we[e]));
}

// A1: pull aggregation; one wave per node; branchless unroll-4 for MLP.
__global__ __launch_bounds__(256) void k_agg(
        const _Float16* __restrict__ xh, const int* __restrict__ rowptr,
        const int* __restrict__ partials, const int* __restrict__ counts,
        const int2* __restrict__ payload, _Float16* __restrict__ aggh,
        int N, int E) {
    int wv = threadIdx.x >> 6, lane = threadIdx.x & 63;
    int n = blockIdx.x * 4 + wv;
    if (n >= N) return;
    int beg = rowptr[n] + partials[n >> 10];
    int cnt = counts[n];
    float ax = 0.f, ay = 0.f;
    for (int i = 0; i < cnt; i += 4) {
        int i0 = beg + i;
        int2 p0 = payload[min(i0 + 0, E - 1)];
        int2 p1 = payload[min(i0 + 1, E - 1)];
        int2 p2 = payload[min(i0 + 2, E - 1)];
        int2 p3 = payload[min(i0 + 3, E - 1)];
        f16x2 v0 = *reinterpret_cast<const f16x2*>(xh + (size_t)p0.x * F + lane * 2);
        f16x2 v1 = *reinterpret_cast<const f16x2*>(xh + (size_t)p1.x * F + lane * 2);
        f16x2 v2 = *reinterpret_cast<const f16x2*>(xh + (size_t)p2.x * F + lane * 2);
        f16x2 v3 = *reinterpret_cast<const f16x2*>(xh + (size_t)p3.x * F + lane * 2);
        float w0 = (i + 0 < cnt) ? __int_as_float(p0.y) : 0.f;
        float w1 = (i + 1 < cnt) ? __int_as_float(p1.y) : 0.f;
        float w2 = (i + 2 < cnt) ? __int_as_float(p2.y) : 0.f;
        float w3 = (i + 3 < cnt) ? __int_as_float(p3.y) : 0.f;
        ax += w0 * (float)v0[0] + w1 * (float)v1[0]
            + w2 * (float)v2[0] + w3 * (float)v3[0];
        ay += w0 * (float)v0[1] + w1 * (float)v1[1]
            + w2 * (float)v2[1] + w3 * (float)v3[1];
    }
    f16x2 o = { (_Float16)ax, (_Float16)ay };
    *reinterpret_cast<f16x2*>(aggh + (size_t)n * F + lane * 2) = o;
}

// ---------------- MFMA GEMM: y = [x, agg] @ W^T, fused column stats ----------
__global__ __launch_bounds__(256) void k_gemm_mfma(
        const _Float16* __restrict__ xh, const _Float16* __restrict__ aggh,
        const _Float16* __restrict__ wh, float* __restrict__ y,
        float* __restrict__ colsum, float* __restrict__ colsumsq, int N) {
    __shared__ float lds_s[4][128], lds_q[4][128];
    int t = threadIdx.x, w = t >> 6, l = t & 63;
    int lo16 = l & 15, hi4 = l >> 4;
    int rows0 = blockIdx.x * 64 + w * 16;
    int row_a = rows0 + lo16;
    if (row_a >= N) row_a = N - 1;          // clamp; results discarded below

    f32x4 acc[8] = {};
    const _Float16* wbase = wh + (size_t)lo16 * 256 + hi4 * 8;
    #pragma unroll
    for (int kb = 0; kb < 8; ++kb) {
        const _Float16* ap = (kb < 4)
            ? (xh   + (size_t)row_a * F + kb * 32 + hi4 * 8)
            : (aggh + (size_t)row_a * F + (kb - 4) * 32 + hi4 * 8);
        f16x8 afrag = *reinterpret_cast<const f16x8*>(ap);
        #pragma unroll
        for (int ct = 0; ct < 8; ++ct) {
            f16x8 bfrag = *reinterpret_cast<const f16x8*>(
                wbase + (size_t)ct * 16 * 256 + kb * 32);
            acc[ct] = __builtin_amdgcn_mfma_f32_16x16x32_f16(
                afrag, bfrag, acc[ct], 0, 0, 0);
        }
    }

    #pragma unroll
    for (int ct = 0; ct < 8; ++ct) {
        float sv = 0.f, qv = 0.f;
        int col = ct * 16 + lo16;
        #pragma unroll
        for (int r = 0; r < 4; ++r) {
            int row = rows0 + hi4 * 4 + r;
            float v = acc[ct][r];
            if (row < N) {
                y[(size_t)row * F + col] = v;
                sv += v;
                qv += v * v;
            }
        }
        sv += __shfl_xor(sv, 16); sv += __shfl_xor(sv, 32);
        qv += __shfl_xor(qv, 16); qv += __shfl_xor(qv, 32);
        if (l < 16) {
            lds_s[w][ct * 16 + l] = sv;
            lds_q[w][ct * 16 + l] = qv;
        }
    }
    __syncthreads();
    if (t < 128) {
        float S = lds_s[0][t] + lds_s[1][t] + lds_s[2][t] + lds_s[3][t];
        float Q = lds_q[0][t] + lds_q[1][t] + lds_q[2][t] + lds_q[3][t];
        atomicAdd(&colsum[t], S);
        atomicAdd(&colsumsq[t], Q);
    }
}

// ---------------- BatchNorm: finalize folded into normalize ----------------
__global__ __launch_bounds__(256) void k_norm(
        float* __restrict__ y, const float* __restrict__ colsum,
        const float* __restrict__ colsumsq, const float* __restrict__ gamma,
        const float* __restrict__ beta, float ninv, int total4) {
    __shared__ float sc_sh[F], sh_sh[F];
    int t = threadIdx.x;
    if (t < F) {
        float mean = colsum[t] * ninv;
        float var = colsumsq[t] * ninv - mean * mean;
        float rstd = rsqrtf(var + EPSV);
        float sc = gamma[t] * rstd;
        sc_sh[t] = sc;
        sh_sh[t] = beta[t] - mean * sc;
    }
    __syncthreads();
    int idx = blockIdx.x * 256 + t;
    if (idx >= total4) return;
    int col4 = (idx & 31) * 4;
    float4 v = *reinterpret_cast<const float4*>(y + (size_t)idx * 4);
    float4 o4;
    o4.x = v.x * sc_sh[col4 + 0] + sh_sh[col4 + 0];
    o4.y = v.y * sc_sh[col4 + 1] + sh_sh[col4 + 1];
    o4.z = v.z * sc_sh[col4 + 2] + sh_sh[col4 + 2];
    o4.w = v.w * sc_sh[col4 + 3] + sh_sh[col4 + 3];
    *reinterpret_cast<float4*>(y + (size_t)idx * 4) = o4;
}

extern "C" void kernel_launch(void* const* d_in, const int* in_sizes, int n_in,
                              void* d_out, int out_size, void* d_ws, size_t ws_size,
                              hipStream_t stream) {
    (void)n_in; (void)out_size; (void)ws_size;
    const float* x     = (const float*)d_in[0];
    const int*   src   = (const int*)d_in[1];
    const int*   dst   = (const int*)d_in[2];
    const float* we    = (const float*)d_in[3];
    const float* W     = (const float*)d_in[4];
    const float* gamma = (const float*)d_in[5];
    const float* beta  = (const float*)d_in[6];
    int N = in_sizes[0] / F;
    int E = in_sizes[1];

    char* ws = (char*)d_ws;
    size_t off = 0;
    auto alloc = [&](size_t bytes) {
        void* p = ws + off;
        off += (bytes + 255) & ~(size_t)255;
        return p;
    };
    _Float16* xh     = (_Float16*)alloc((size_t)N * F * sizeof(_Float16));
    _Float16* aggh   = (_Float16*)alloc((size_t)N * F * sizeof(_Float16));
    _Float16* wh     = (_Float16*)alloc((size_t)F * 2 * F * sizeof(_Float16));
    float* stats     = (float*)alloc(2 * F * sizeof(float));   // colsum | colsumsq
    int*   counts    = (int*)alloc((size_t)N * sizeof(int));
    int*   rowptr    = (int*)alloc((size_t)N * sizeof(int));
    int*   partials  = (int*)alloc(1024 * sizeof(int));
    int*   rank      = (int*)alloc((size_t)E * sizeof(int));
    int2*  payload   = (int2*)alloc((size_t)E * sizeof(int2));
    float* colsum    = stats;
    float* colsumsq  = stats + F;

    float* y = (float*)d_out;

    // conversions (+ counts zeroing piggybacked on k_cvt_x)
    int n4x = N * F / 4;
    hipLaunchKernelGGL(k_cvt_x, dim3((n4x + 255) / 256), dim3(256), 0, stream,
                       x, xh, n4x, counts, (N + 3) / 4);
    hipLaunchKernelGGL(k_cvt_w, dim3((2 * F * F / 4 + 255) / 256), dim3(256), 0, stream,
                       W, wh, 2 * F * F / 4);

    // CSR build (rank from histogram; no cursor atomics)
    int nchunks = (N + 1023) / 1024;
    hipLaunchKernelGGL(k_hist, dim3((E + 255) / 256), dim3(256), 0, stream,
                       dst, counts, rank, E);
    hipLaunchKernelGGL(k_scan1, dim3(nchunks), dim3(256), 0, stream,
                       counts, rowptr, partials, N);
    hipLaunchKernelGGL(k_scan2, dim3(1), dim3(64), 0, stream,
                       partials, nchunks, stats);
    hipLaunchKernelGGL(k_fill, dim3((E + 255) / 256), dim3(256), 0, stream,
                       dst, rank, rowptr, partials, src, we, payload, E);

    // aggregation (pull, packed payload, unroll-4)
    hipLaunchKernelGGL(k_agg, dim3((N + 3) / 4), dim3(256), 0, stream,
                       xh, rowptr, partials, counts, payload, aggh, N, E);

    // MFMA GEMM + fused stats
    hipLaunchKernelGGL(k_gemm_mfma, dim3((N + 63) / 64), dim3(256), 0, stream,
                       xh, aggh, wh, y, colsum, colsumsq, N);

    // BN finalize + normalize in place
    hipLaunchKernelGGL(k_norm, dim3((N * 32 + 255) / 256), dim3(256), 0, stream,
                       y, colsum, colsumsq, gamma, beta, 1.0f / (float)N, N * 32);
}

// Round 8
// 136.113 us; speedup vs baseline: 11.2992x; 1.2413x over previous
//
#include <hip/hip_runtime.h>

#define F 128            // F_IN == F_OUT == 128
#define EPSV 1e-5f

typedef _Float16 f16x8 __attribute__((ext_vector_type(8)));
typedef _Float16 f16x4 __attribute__((ext_vector_type(4)));
typedef _Float16 f16x2 __attribute__((ext_vector_type(2)));
typedef float    f32x4 __attribute__((ext_vector_type(4)));

// ---------------- x f32->f16 + zero counts ----------------
__global__ __launch_bounds__(256) void k_cvt_x(
        const float* __restrict__ in, _Float16* __restrict__ out, int n4,
        int* __restrict__ counts, int ncnt4) {
    int i = blockIdx.x * 256 + threadIdx.x;
    if (i < ncnt4)  // counts alloc is 256B-padded; int4 overshoot is safe
        *reinterpret_cast<int4*>(counts + i * 4) = make_int4(0, 0, 0, 0);
    if (i >= n4) return;
    float4 v = *reinterpret_cast<const float4*>(in + (size_t)i * 4);
    f16x4 o = { (_Float16)v.x, (_Float16)v.y, (_Float16)v.z, (_Float16)v.w };
    *reinterpret_cast<f16x4*>(out + (size_t)i * 4) = o;
}

// ---------------- W f32->f16 ----------------
__global__ __launch_bounds__(256) void k_cvt_w(
        const float* __restrict__ in, _Float16* __restrict__ out, int n4) {
    int i = blockIdx.x * 256 + threadIdx.x;
    if (i >= n4) return;
    float4 v = *reinterpret_cast<const float4*>(in + (size_t)i * 4);
    f16x4 o = { (_Float16)v.x, (_Float16)v.y, (_Float16)v.z, (_Float16)v.w };
    *reinterpret_cast<f16x4*>(out + (size_t)i * 4) = o;
}

// ---------------- CSR build ----------------
__global__ __launch_bounds__(256) void k_hist(
        const int* __restrict__ dst, int* __restrict__ counts,
        int* __restrict__ rank, int E) {
    int e = blockIdx.x * 256 + threadIdx.x;
    if (e < E) rank[e] = atomicAdd(&counts[dst[e]], 1);
}

__global__ __launch_bounds__(256) void k_scan1(
        const int* __restrict__ counts, int* __restrict__ rowptr,
        int* __restrict__ partials, int N) {
    __shared__ int wsum[4];
    int t = threadIdx.x;
    int base = blockIdx.x * 1024;
    int lane = t & 63, wv = t >> 6;
    int v[4], s = 0;
    #pragma unroll
    for (int i = 0; i < 4; ++i) {
        int idx = base + t * 4 + i;
        v[i] = (idx < N) ? counts[idx] : 0;
        s += v[i];
    }
    int sc = s;
    #pragma unroll
    for (int off = 1; off < 64; off <<= 1) {
        int o = __shfl_up(sc, off);
        if (lane >= off) sc += o;
    }
    if (lane == 63) wsum[wv] = sc;
    __syncthreads();
    int woff = 0;
    for (int i = 0; i < wv; ++i) woff += wsum[i];
    int excl = woff + sc - s;
    #pragma unroll
    for (int i = 0; i < 4; ++i) {
        int idx = base + t * 4 + i;
        if (idx < N) rowptr[idx] = excl;
        excl += v[i];
    }
    if (t == 255) partials[blockIdx.x] = woff + sc;
}

__global__ void k_scan2(int* __restrict__ partials, int nb,
                        float* __restrict__ stats) {
    int t = threadIdx.x;  // 64 threads
    *reinterpret_cast<float4*>(stats + t * 4) = make_float4(0.f, 0.f, 0.f, 0.f);
    int carry = 0;
    for (int b = 0; b < nb; b += 64) {
        int i = b + t;
        int v = (i < nb) ? partials[i] : 0;
        int sc = v;
        #pragma unroll
        for (int off = 1; off < 64; off <<= 1) {
            int o = __shfl_up(sc, off);
            if (t >= off) sc += o;
        }
        if (i < nb) partials[i] = carry + sc - v;
        carry += __shfl(sc, 63);
    }
}

__global__ __launch_bounds__(256) void k_fill(
        const int* __restrict__ dst, const int* __restrict__ rank,
        const int* __restrict__ rowptr, const int* __restrict__ partials,
        const int* __restrict__ src, const float* __restrict__ we,
        int2* __restrict__ payload, int E) {
    int e = blockIdx.x * 256 + threadIdx.x;
    if (e >= E) return;
    int d = dst[e];
    int slot = rowptr[d] + partials[d >> 10] + rank[e];
    payload[slot] = make_int2(src[e], __float_as_int(we[e]));
}

// A1: pull aggregation; one wave per node; branchless unroll-8 for MLP.
__global__ __launch_bounds__(256) void k_agg(
        const _Float16* __restrict__ xh, const int* __restrict__ rowptr,
        const int* __restrict__ partials, const int* __restrict__ counts,
        const int2* __restrict__ payload, _Float16* __restrict__ aggh,
        int N, int E) {
    int wv = threadIdx.x >> 6, lane = threadIdx.x & 63;
    int n = blockIdx.x * 4 + wv;
    if (n >= N) return;
    int beg = rowptr[n] + partials[n >> 10];
    int cnt = counts[n];
    float ax = 0.f, ay = 0.f;
    for (int i = 0; i < cnt; i += 8) {
        int i0 = beg + i;
        int2 p[8];
        #pragma unroll
        for (int u = 0; u < 8; ++u)
            p[u] = payload[min(i0 + u, E - 1)];
        f16x2 v[8];
        #pragma unroll
        for (int u = 0; u < 8; ++u)
            v[u] = *reinterpret_cast<const f16x2*>(xh + (size_t)p[u].x * F + lane * 2);
        #pragma unroll
        for (int u = 0; u < 8; ++u) {
            float wu = (i + u < cnt) ? __int_as_float(p[u].y) : 0.f;
            ax += wu * (float)v[u][0];
            ay += wu * (float)v[u][1];
        }
    }
    f16x2 o = { (_Float16)ax, (_Float16)ay };
    *reinterpret_cast<f16x2*>(aggh + (size_t)n * F + lane * 2) = o;
}

// ---------------- MFMA GEMM: y = [x, agg] @ W^T, fused column stats ----------
// 256 threads = 4 waves; W staged in swizzled LDS; each wave: 32 rows
// (2 row-tiles of 16), 8 col-tiles of 16, K = 256 in 8 steps of 32.
__global__ __launch_bounds__(256) void k_gemm_mfma(
        const _Float16* __restrict__ xh, const _Float16* __restrict__ aggh,
        const _Float16* __restrict__ wh, _Float16* __restrict__ yh,
        float* __restrict__ colsum, float* __restrict__ colsumsq, int N) {
    __shared__ _Float16 lds_w[32768];                 // 64 KB, XOR-swizzled
    __shared__ float lds_s[4][128], lds_q[4][128];
    int t = threadIdx.x, w = t >> 6, l = t & 63;
    int lo16 = l & 15, hi4 = l >> 4;

    // stage W: 4096 chunks of 16B (8 f16); 32 chunks per 512B row.
    // swizzle: byte ^= (o&7)<<4 (bits 4-6), bijective within each row.
    #pragma unroll
    for (int i = 0; i < 16; ++i) {
        int c = i * 256 + t;
        int o = c >> 5, kc = c & 31;      // FIXED: 32 chunks/row (was >>4/&15: OOB)
        f16x8 v = *reinterpret_cast<const f16x8*>(wh + (size_t)c * 8);
        int byte = (o * 512 + kc * 16) ^ ((o & 7) << 4);
        *reinterpret_cast<f16x8*>((char*)lds_w + byte) = v;
    }
    __syncthreads();

    int rows0 = blockIdx.x * 128 + w * 32;
    int ra0 = rows0 + lo16, ra1 = rows0 + 16 + lo16;
    if (ra0 >= N) ra0 = N - 1;                // clamp; discarded in epilogue
    if (ra1 >= N) ra1 = N - 1;

    f32x4 acc0[8] = {}, acc1[8] = {};
    #pragma unroll
    for (int kb = 0; kb < 8; ++kb) {
        const _Float16* base = (kb < 4) ? xh : aggh;
        int koff = (kb & 3) * 32 + hi4 * 8;
        f16x8 a0 = *reinterpret_cast<const f16x8*>(base + (size_t)ra0 * F + koff);
        f16x8 a1 = *reinterpret_cast<const f16x8*>(base + (size_t)ra1 * F + koff);
        #pragma unroll
        for (int ct = 0; ct < 8; ++ct) {
            int o = ct * 16 + lo16;
            int byte = (o * 512 + kb * 64 + hi4 * 16) ^ ((o & 7) << 4);
            f16x8 b = *reinterpret_cast<const f16x8*>((char*)lds_w + byte);
            acc0[ct] = __builtin_amdgcn_mfma_f32_16x16x32_f16(a0, b, acc0[ct], 0, 0, 0);
            acc1[ct] = __builtin_amdgcn_mfma_f32_16x16x32_f16(a1, b, acc1[ct], 0, 0, 0);
        }
    }

    // epilogue: f16 y-write + column sum/sumsq reduce
    #pragma unroll
    for (int ct = 0; ct < 8; ++ct) {
        float sv = 0.f, qv = 0.f;
        int col = ct * 16 + lo16;
        #pragma unroll
        for (int r = 0; r < 4; ++r) {
            int row0 = rows0 + hi4 * 4 + r;
            float v0 = acc0[ct][r];
            if (row0 < N) {
                yh[(size_t)row0 * F + col] = (_Float16)v0;
                sv += v0; qv += v0 * v0;
            }
            int row1 = rows0 + 16 + hi4 * 4 + r;
            float v1 = acc1[ct][r];
            if (row1 < N) {
                yh[(size_t)row1 * F + col] = (_Float16)v1;
                sv += v1; qv += v1 * v1;
            }
        }
        sv += __shfl_xor(sv, 16); sv += __shfl_xor(sv, 32);
        qv += __shfl_xor(qv, 16); qv += __shfl_xor(qv, 32);
        if (l < 16) {
            lds_s[w][col] = sv;
            lds_q[w][col] = qv;
        }
    }
    __syncthreads();
    if (t < 128) {
        float S = lds_s[0][t] + lds_s[1][t] + lds_s[2][t] + lds_s[3][t];
        float Q = lds_q[0][t] + lds_q[1][t] + lds_q[2][t] + lds_q[3][t];
        atomicAdd(&colsum[t], S);
        atomicAdd(&colsumsq[t], Q);
    }
}

// ---------------- BatchNorm: finalize + normalize (f16 y -> f32 out) --------
__global__ __launch_bounds__(256) void k_norm(
        const _Float16* __restrict__ yh, float* __restrict__ out,
        const float* __restrict__ colsum, const float* __restrict__ colsumsq,
        const float* __restrict__ gamma, const float* __restrict__ beta,
        float ninv, int total8) {
    __shared__ float sc_sh[F], sh_sh[F];
    int t = threadIdx.x;
    if (t < F) {
        float mean = colsum[t] * ninv;
        float var = colsumsq[t] * ninv - mean * mean;
        float rstd = rsqrtf(var + EPSV);
        float sc = gamma[t] * rstd;
        sc_sh[t] = sc;
        sh_sh[t] = beta[t] - mean * sc;
    }
    __syncthreads();
    int idx = blockIdx.x * 256 + t;
    if (idx >= total8) return;
    int col8 = (idx & 15) * 8;
    f16x8 v = *reinterpret_cast<const f16x8*>(yh + (size_t)idx * 8);
    float4 o0, o1;
    o0.x = (float)v[0] * sc_sh[col8 + 0] + sh_sh[col8 + 0];
    o0.y = (float)v[1] * sc_sh[col8 + 1] + sh_sh[col8 + 1];
    o0.z = (float)v[2] * sc_sh[col8 + 2] + sh_sh[col8 + 2];
    o0.w = (float)v[3] * sc_sh[col8 + 3] + sh_sh[col8 + 3];
    o1.x = (float)v[4] * sc_sh[col8 + 4] + sh_sh[col8 + 4];
    o1.y = (float)v[5] * sc_sh[col8 + 5] + sh_sh[col8 + 5];
    o1.z = (float)v[6] * sc_sh[col8 + 6] + sh_sh[col8 + 6];
    o1.w = (float)v[7] * sc_sh[col8 + 7] + sh_sh[col8 + 7];
    *reinterpret_cast<float4*>(out + (size_t)idx * 8)     = o0;
    *reinterpret_cast<float4*>(out + (size_t)idx * 8 + 4) = o1;
}

extern "C" void kernel_launch(void* const* d_in, const int* in_sizes, int n_in,
                              void* d_out, int out_size, void* d_ws, size_t ws_size,
                              hipStream_t stream) {
    (void)n_in; (void)out_size; (void)ws_size;
    const float* x     = (const float*)d_in[0];
    const int*   src   = (const int*)d_in[1];
    const int*   dst   = (const int*)d_in[2];
    const float* we    = (const float*)d_in[3];
    const float* W     = (const float*)d_in[4];
    const float* gamma = (const float*)d_in[5];
    const float* beta  = (const float*)d_in[6];
    int N = in_sizes[0] / F;
    int E = in_sizes[1];

    char* ws = (char*)d_ws;
    size_t off = 0;
    auto alloc = [&](size_t bytes) {
        void* p = ws + off;
        off += (bytes + 255) & ~(size_t)255;
        return p;
    };
    _Float16* xh     = (_Float16*)alloc((size_t)N * F * sizeof(_Float16));
    _Float16* aggh   = (_Float16*)alloc((size_t)N * F * sizeof(_Float16));
    _Float16* yh     = (_Float16*)alloc((size_t)N * F * sizeof(_Float16));
    _Float16* wh     = (_Float16*)alloc((size_t)F * 2 * F * sizeof(_Float16));
    float* stats     = (float*)alloc(2 * F * sizeof(float));   // colsum | colsumsq
    int*   counts    = (int*)alloc((size_t)N * sizeof(int));
    int*   rowptr    = (int*)alloc((size_t)N * sizeof(int));
    int*   partials  = (int*)alloc(1024 * sizeof(int));
    int*   rank      = (int*)alloc((size_t)E * sizeof(int));
    int2*  payload   = (int2*)alloc((size_t)E * sizeof(int2));
    float* colsum    = stats;
    float* colsumsq  = stats + F;

    float* y = (float*)d_out;

    // conversions (+ counts zeroing piggybacked on k_cvt_x)
    int n4x = N * F / 4;
    hipLaunchKernelGGL(k_cvt_x, dim3((n4x + 255) / 256), dim3(256), 0, stream,
                       x, xh, n4x, counts, (N + 3) / 4);
    hipLaunchKernelGGL(k_cvt_w, dim3((2 * F * F / 4 + 255) / 256), dim3(256), 0, stream,
                       W, wh, 2 * F * F / 4);

    // CSR build (rank from histogram; no cursor atomics)
    int nchunks = (N + 1023) / 1024;
    hipLaunchKernelGGL(k_hist, dim3((E + 255) / 256), dim3(256), 0, stream,
                       dst, counts, rank, E);
    hipLaunchKernelGGL(k_scan1, dim3(nchunks), dim3(256), 0, stream,
                       counts, rowptr, partials, N);
    hipLaunchKernelGGL(k_scan2, dim3(1), dim3(64), 0, stream,
                       partials, nchunks, stats);
    hipLaunchKernelGGL(k_fill, dim3((E + 255) / 256), dim3(256), 0, stream,
                       dst, rank, rowptr, partials, src, we, payload, E);

    // aggregation (pull, packed payload, unroll-8)
    hipLaunchKernelGGL(k_agg, dim3((N + 3) / 4), dim3(256), 0, stream,
                       xh, rowptr, partials, counts, payload, aggh, N, E);

    // MFMA GEMM (W in LDS) + fused stats
    hipLaunchKernelGGL(k_gemm_mfma, dim3((N + 127) / 128), dim3(256), 0, stream,
                       xh, aggh, wh, yh, colsum, colsumsq, N);

    // BN finalize + normalize (f16 y -> f32 out)
    hipLaunchKernelGGL(k_norm, dim3((N * F / 8 + 255) / 256), dim3(256), 0, stream,
                       yh, y, colsum, colsumsq, gamma, beta, 1.0f / (float)N, N * F / 8);
}